// Round 2
// baseline (502.260 us; speedup 1.0000x reference)
//
#include <hip/hip_runtime.h>
#include <math.h>

#define BB 128
#define NN 128
#define DIN 1024
#define H1 256
#define DOUT 32
#define KCL 8
#define NPTS 128
#define MROWS (BB*NN)   // 16384
#define CSTR 130        // centsT row stride (words, init staging only)
#define RSTR 132        // cost/G row stride (words, 16B aligned)
#define DEADKEY  0xFFFFFFFF00000000ull
#define INVALIDK 0xFFFFFFFFFFFFFFFFull

__device__ __forceinline__ float gelu_exact(float v) {
    return 0.5f * v * (1.0f + erff(v * 0.70710678118654752f));
}

__device__ __forceinline__ unsigned long long mkkey(float v, int r, int j) {
    return ((unsigned long long)__float_as_uint(v) << 32) | (unsigned)((r << 7) | j);
}

__device__ __forceinline__ float readlanef(float v, int lane) {
    return __int_as_float(__builtin_amdgcn_readlane(__float_as_int(v), lane));
}

// u32 min via DPP (costs are >=0 floats: IEEE order == unsigned bit order)
template<int CTRL, int RMASK>
__device__ __forceinline__ unsigned dpp_umin_step(unsigned v) {
    unsigned t = (unsigned)__builtin_amdgcn_update_dpp((int)v, (int)v, CTRL, RMASK, 0xf, false);
    return t < v ? t : v;
}
__device__ __forceinline__ unsigned wave_umin_bcast(unsigned v) {
    v = dpp_umin_step<0x111, 0xf>(v);
    v = dpp_umin_step<0x112, 0xf>(v);
    v = dpp_umin_step<0x114, 0xf>(v);
    v = dpp_umin_step<0x118, 0xf>(v);
    v = dpp_umin_step<0x142, 0xa>(v);
    v = dpp_umin_step<0x143, 0xc>(v);
    return (unsigned)__builtin_amdgcn_readlane((int)v, 63);
}
// lane31 = min(lanes0..31), lane63 = min(lanes32..63)
__device__ __forceinline__ unsigned half_umin(unsigned v) {
    v = dpp_umin_step<0x111, 0xf>(v);
    v = dpp_umin_step<0x112, 0xf>(v);
    v = dpp_umin_step<0x114, 0xf>(v);
    v = dpp_umin_step<0x118, 0xf>(v);
    v = dpp_umin_step<0x142, 0xa>(v);
    return v;
}

// Exact top-2 per-row key maintenance under ward merge (i2,j2):
//  - k  = exact min key of the row (val<<32 | r<<7 | col)
//  - kb = exact second-min key, or INVALIDK if unknown
// Row values change only at col i2 (new value v) and col j2 (deleted).
__device__ __forceinline__ void top2_update(unsigned long long &k, unsigned long long &kb,
                                            bool &dirty, float v, int r, int i2, int j2) {
    int ck = (int)(k & 127u);
    bool pk = (ck == i2) || (ck == j2);
    bool sval = (kb != INVALIDK);
    int cs = (int)(kb & 127u);
    bool ps = sval && ((cs == i2) || (cs == j2));
    if (pk) {
        if (sval && !ps) { k = kb; }   // promote exact second to min
        else { dirty = true; }         // second unavailable -> LDS rescan
        kb = INVALIDK;
    } else if (ps) {
        kb = INVALIDK;
    }
    if (!dirty) {
        unsigned long long kn = mkkey(v, r, i2);
        if (kn < k) { kb = k; k = kn; }
        else if (kb != INVALIDK && kn < kb) kb = kn;
    }
}

// ---------------- gelu precompute: gx = gelu(x), memory-bound ----------------
__global__ __launch_bounds__(256) void gelu_kernel(const float* __restrict__ x,
                                                   float* __restrict__ gx, int n4) {
    int i = blockIdx.x * 256 + threadIdx.x;
    const int stride = gridDim.x * 256;
    for (; i < n4; i += stride) {
        float4 v = ((const float4*)x)[i];
        v.x = gelu_exact(v.x);
        v.y = gelu_exact(v.y);
        v.z = gelu_exact(v.z);
        v.w = gelu_exact(v.w);
        ((float4*)gx)[i] = v;
    }
}

// ---------------- GEMM1: h = A @ W1 + b1 ; 128x128 tile, 8x8 microtile, BK=16 ----------------
// 256 blocks (1/CU), 256 threads, register-prefetched staging.
// FUSE=true: A = gelu(x) applied at staging (fallback). FUSE=false: A = gx (pre-gelu'd).
template<bool FUSE>
__global__ __launch_bounds__(256) void mlp1_kernel(const float* __restrict__ xin,
                                                   const float* __restrict__ W1,
                                                   const float* __restrict__ b1,
                                                   float* __restrict__ h) {
    __shared__ float As[16][132];  // [k][m]
    __shared__ float Bs[16][132];  // [k][n]
    const int bm = blockIdx.x;     // 128 row-tiles of 128
    const int bn = blockIdx.y;     // 2 col-tiles of 128
    const int tid = threadIdx.x;
    const int tx = tid & 15;       // col quad 0..15
    const int ty = tid >> 4;       // row quad 0..15

    float acc[8][8];
#pragma unroll
    for (int i = 0; i < 8; ++i)
#pragma unroll
        for (int j = 0; j < 8; ++j) acc[i][j] = 0.f;

    const int arow = tid >> 1;        // 0..127
    const int ak8  = (tid & 1) * 8;   // 0 or 8
    const int bk   = tid >> 4;        // 0..15
    const int bcol = (tid & 15) * 8;  // 0..120

    const float* xrow = xin + (size_t)(bm * 128 + arow) * DIN;
    const float* wbase = W1 + bn * 128;

    // prefetch first tile
    float4 a0 = *(const float4*)(xrow + ak8);
    float4 a1 = *(const float4*)(xrow + ak8 + 4);
    float4 w0 = *(const float4*)(wbase + (size_t)bk * H1 + bcol);
    float4 w1 = *(const float4*)(wbase + (size_t)bk * H1 + bcol + 4);

    for (int kt = 0; kt < DIN; kt += 16) {
        __syncthreads();
        if (FUSE) {
            As[ak8 + 0][arow] = gelu_exact(a0.x);
            As[ak8 + 1][arow] = gelu_exact(a0.y);
            As[ak8 + 2][arow] = gelu_exact(a0.z);
            As[ak8 + 3][arow] = gelu_exact(a0.w);
            As[ak8 + 4][arow] = gelu_exact(a1.x);
            As[ak8 + 5][arow] = gelu_exact(a1.y);
            As[ak8 + 6][arow] = gelu_exact(a1.z);
            As[ak8 + 7][arow] = gelu_exact(a1.w);
        } else {
            As[ak8 + 0][arow] = a0.x;
            As[ak8 + 1][arow] = a0.y;
            As[ak8 + 2][arow] = a0.z;
            As[ak8 + 3][arow] = a0.w;
            As[ak8 + 4][arow] = a1.x;
            As[ak8 + 5][arow] = a1.y;
            As[ak8 + 6][arow] = a1.z;
            As[ak8 + 7][arow] = a1.w;
        }
        *(float4*)&Bs[bk][bcol] = w0;
        *(float4*)&Bs[bk][bcol + 4] = w1;
        __syncthreads();
        if (kt + 16 < DIN) {  // prefetch next tile; overlaps the FMA block below
            a0 = *(const float4*)(xrow + kt + 16 + ak8);
            a1 = *(const float4*)(xrow + kt + 16 + ak8 + 4);
            w0 = *(const float4*)(wbase + (size_t)(kt + 16 + bk) * H1 + bcol);
            w1 = *(const float4*)(wbase + (size_t)(kt + 16 + bk) * H1 + bcol + 4);
        }
#pragma unroll
        for (int kk = 0; kk < 16; ++kk) {
            float4 aL = *(const float4*)&As[kk][ty * 4];
            float4 aH = *(const float4*)&As[kk][64 + ty * 4];
            float4 bL = *(const float4*)&Bs[kk][tx * 4];
            float4 bH = *(const float4*)&Bs[kk][64 + tx * 4];
            float ar[8] = {aL.x, aL.y, aL.z, aL.w, aH.x, aH.y, aH.z, aH.w};
            float br[8] = {bL.x, bL.y, bL.z, bL.w, bH.x, bH.y, bH.z, bH.w};
#pragma unroll
            for (int i = 0; i < 8; ++i)
#pragma unroll
                for (int j = 0; j < 8; ++j)
                    acc[i][j] = fmaf(ar[i], br[j], acc[i][j]);
        }
    }

    const int row0 = bm * 128 + ty * 4;
    const int col0 = bn * 128 + tx * 4;
    float4 biasL = *(const float4*)(b1 + col0);
    float4 biasH = *(const float4*)(b1 + col0 + 64);
#pragma unroll
    for (int i = 0; i < 8; ++i) {
        int rr = (i < 4) ? i : (64 + i - 4);
        float4 oL, oH;
        oL.x = acc[i][0] + biasL.x;
        oL.y = acc[i][1] + biasL.y;
        oL.z = acc[i][2] + biasL.z;
        oL.w = acc[i][3] + biasL.w;
        oH.x = acc[i][4] + biasH.x;
        oH.y = acc[i][5] + biasH.y;
        oH.z = acc[i][6] + biasH.z;
        oH.w = acc[i][7] + biasH.w;
        *(float4*)(h + (size_t)(row0 + rr) * H1 + col0) = oL;
        *(float4*)(h + (size_t)(row0 + rr) * H1 + col0 + 64) = oH;
    }
}

// ---------------- GEMM2: feats = gelu(h) @ W2 + b2 (best-measured R4 version) ----------------
__global__ __launch_bounds__(256) void mlp2_kernel(const float* __restrict__ h,
                                                   const float* __restrict__ W2,
                                                   const float* __restrict__ b2,
                                                   float* __restrict__ feats) {
    __shared__ float hs[16][257];
    __shared__ float w2s[H1 * DOUT];
    const int blk = blockIdx.x;
    const int tid = threadIdx.x;

    for (int i = tid; i < (H1 * DOUT) / 4; i += 256) {
        ((float4*)w2s)[i] = ((const float4*)W2)[i];
    }
    const float* hb = h + (size_t)blk * 16 * H1;
    for (int i = tid; i < (16 * H1) / 4; i += 256) {
        float4 v = ((const float4*)hb)[i];
        int r = i >> 6;
        int c = (i & 63) * 4;
        hs[r][c + 0] = gelu_exact(v.x);
        hs[r][c + 1] = gelu_exact(v.y);
        hs[r][c + 2] = gelu_exact(v.z);
        hs[r][c + 3] = gelu_exact(v.w);
    }
    __syncthreads();

    const int col = tid & 31;
    const int r0 = (tid >> 5) * 2;
    float acc0 = 0.f, acc1 = 0.f;
    for (int k = 0; k < H1; ++k) {
        float w = w2s[k * DOUT + col];
        acc0 = fmaf(hs[r0 + 0][k], w, acc0);
        acc1 = fmaf(hs[r0 + 1][k], w, acc1);
    }
    float bias = b2[col];
    const int rowg = blk * 16 + r0;
    feats[(size_t)(rowg + 0) * DOUT + col] = acc0 + bias;
    feats[(size_t)(rowg + 1) * DOUT + col] = acc1 + bias;
}

// ---------------- Ward clustering: incremental Gram + exact in-register top-2 keys ----------------
// Changes vs prior version (bit-exact by construction):
//  * row-i2 key computed from the in-register v0/v1 values (no LDS rescan of row i2)
//  * exact (min, second-min) keys per row -> dirty LDS rescans only when both purged
__global__ __launch_bounds__(256) void ward_kernel(const float* __restrict__ feats,
                                                   int* __restrict__ out) {
    __shared__ __align__(16) float cost[NPTS * RSTR];  // 67.6 KB
    __shared__ __align__(16) float G[NPTS * RSTR];     // 67.6 KB Gram matrix
    __shared__ float centsT[32 * CSTR];                // init staging only
    __shared__ unsigned long long rowkey[NPTS];
    __shared__ unsigned long long rowsec[NPTS];
    __shared__ float sqArr[NPTS];
    __shared__ float szsE[NPTS];
    __shared__ int rnk[NPTS];

    const int b = blockIdx.x;
    const int tid = threadIdx.x;
    const float* f = feats + (size_t)b * NPTS * DOUT;
    const float INF = __builtin_inff();

    // ---- init (all 4 waves) ----
    for (int i = tid; i < NPTS * DOUT; i += 256) {
        int r = i >> 5, d = i & 31;
        centsT[d * CSTR + r] = f[i];
    }
    __syncthreads();
    if (tid < NPTS) {
        float s = 0.f;
#pragma unroll
        for (int d = 0; d < 32; ++d) {
            float v = centsT[d * CSTR + tid];
            s = fmaf(v, v, s);
        }
        sqArr[tid] = s;
    }
    __syncthreads();
    {
        int ti = tid >> 4, tj = tid & 15;
        int I0 = ti * 8, J0 = tj * 8;
        float acc[8][8];
#pragma unroll
        for (int u = 0; u < 8; ++u)
#pragma unroll
            for (int v = 0; v < 8; ++v) acc[u][v] = 0.f;
        for (int d = 0; d < 32; ++d) {
            float a[8], bb[8];
#pragma unroll
            for (int u = 0; u < 8; ++u) a[u] = centsT[d * CSTR + I0 + u];
#pragma unroll
            for (int v = 0; v < 8; ++v) bb[v] = centsT[d * CSTR + J0 + v];
#pragma unroll
            for (int u = 0; u < 8; ++u)
#pragma unroll
                for (int v = 0; v < 8; ++v)
                    acc[u][v] = fmaf(a[u], bb[v], acc[u][v]);
        }
#pragma unroll
        for (int u = 0; u < 8; ++u) {
#pragma unroll
            for (int v = 0; v < 8; ++v) {
                int i = I0 + u, j = J0 + v;
                G[i * RSTR + j] = acc[u][v];
                float d2 = sqArr[i] + sqArr[j] - 2.0f * acc[u][v];
                if (d2 < 0.f) d2 = 0.f;
                float w = (1.0f * 1.0f) / (1.0f + 1.0f + 1e-30f);
                cost[i * RSTR + j] = (i == j) ? INF : w * d2;
            }
        }
    }
    __syncthreads();
    if (tid < NPTS) {
        // exact top-2 scan of the row (float4)
        unsigned long long best = INVALIDK, sec = INVALIDK;
        const float* cr = &cost[tid * RSTR];
        for (int j4 = 0; j4 < NPTS / 4; ++j4) {
            float4 v = *(const float4*)(cr + 4 * j4);
            unsigned long long kx;
            kx = mkkey(v.x, tid, 4 * j4 + 0);
            if (kx < best) { sec = best; best = kx; } else if (kx < sec) sec = kx;
            kx = mkkey(v.y, tid, 4 * j4 + 1);
            if (kx < best) { sec = best; best = kx; } else if (kx < sec) sec = kx;
            kx = mkkey(v.z, tid, 4 * j4 + 2);
            if (kx < best) { sec = best; best = kx; } else if (kx < sec) sec = kx;
            kx = mkkey(v.w, tid, 4 * j4 + 3);
            if (kx < best) { sec = best; best = kx; } else if (kx < sec) sec = kx;
        }
        rowkey[tid] = best;
        rowsec[tid] = sec;
    }
    __syncthreads();

    if (tid >= 64) return;  // wave 0 only
    const int lane = tid;
    const int hh = lane & 31;
    const int r0 = lane * 2, r1 = lane * 2 + 1;

    unsigned long long k0 = rowkey[r0], k1 = rowkey[r1];
    unsigned long long k0b = rowsec[r0], k1b = rowsec[r1];
    float q0 = sqArr[r0], q1 = sqArr[r1];
    float s0 = 1.0f, s1 = 1.0f;
    int lab0 = r0, lab1 = r1;
    unsigned long long alive0 = ~0ull, alive1 = ~0ull;

    for (int it = 0; it < NPTS - KCL; ++it) {
        // P1: global argmin via u32-bits DPP min + ballot (exact flat-index tie-break)
        unsigned bv0 = (unsigned)(k0 >> 32), bv1 = (unsigned)(k1 >> 32);
        unsigned lmin = bv0 < bv1 ? bv0 : bv1;
        unsigned lflat = (bv0 <= bv1) ? (unsigned)(k0 & 0x3FFFu) : (unsigned)(k1 & 0x3FFFu);
        unsigned gmin = wave_umin_bcast(lmin);
        unsigned long long bmask = __ballot(lmin == gmin);
        int lsel = __ffsll(bmask) - 1;
        unsigned flat = (unsigned)__builtin_amdgcn_readlane((int)lflat, lsel);
        int ra = (int)(flat >> 7), ca = (int)(flat & 127u);
        const int i2 = ra < ca ? ra : ca;
        const int j2 = ra < ca ? ca : ra;

        // Gram rows i2, j2 (issued early; only depend on i2/j2)
        float2 gi = *(const float2*)&G[i2 * RSTR + r0];
        float2 gj = *(const float2*)&G[j2 * RSTR + r0];

        float si = readlanef((i2 & 1) ? s1 : s0, i2 >> 1);
        float sj = readlanef((j2 & 1) ? s1 : s0, j2 >> 1);
        const float snew = si + sj;
        const float invs = 1.0f / snew;
        const float wa = si * invs, wb = sj * invs;

        // scalar Gram entries for qn
        float Gii = readlanef((i2 & 1) ? gi.y : gi.x, i2 >> 1);
        float Gij = readlanef((i2 & 1) ? gj.y : gj.x, i2 >> 1);
        float Gjj = readlanef((j2 & 1) ? gj.y : gj.x, j2 >> 1);
        float dotA = wa * Gii + wb * Gij;
        float dotB = wa * Gij + wb * Gjj;
        float qn = wa * dotA + wb * dotB;

        // per-lane dots with merged cluster (linear Gram update)
        float dot0 = wa * gi.x + wb * gj.x;
        float dot1 = wa * gi.y + wb * gj.y;

        // state updates
        if (lab0 == j2) lab0 = i2;
        if (lab1 == j2) lab1 = i2;
        if (r0 == i2) s0 = snew; else if (r0 == j2) { s0 = 0.f; k0 = DEADKEY; k0b = INVALIDK; }
        if (r1 == i2) s1 = snew; else if (r1 == j2) { s1 = 0.f; k1 = DEADKEY; k1b = INVALIDK; }
        if (j2 < 64) alive0 &= ~(1ull << j2); else alive1 &= ~(1ull << (j2 - 64));
        if (r0 == i2) { dot0 = qn; q0 = qn; }
        if (r1 == i2) { dot1 = qn; q1 = qn; }

        // G updates: row i2 (contiguous b64), column i2
        *(float2*)&G[i2 * RSTR + r0] = make_float2(dot0, dot1);
        G[r0 * RSTR + i2] = dot0;
        G[r1 * RSTR + i2] = dot1;

        // new cost values for row/col i2
        bool w0 = (s0 > 0.f) && r0 != i2 && r0 != j2;
        bool w1 = (s1 > 0.f) && r1 != i2 && r1 != j2;
        float v0 = 0.f, v1 = 0.f;
        unsigned uv0 = 0xFFFFFFFFu, uv1 = 0xFFFFFFFFu;
        if (w0) {
            float d2 = q0 + qn - 2.0f * dot0;
            if (d2 < 0.f) d2 = 0.f;
            float w = (s0 * snew) / (s0 + snew + 1e-30f);
            v0 = w * d2;
            cost[r0 * RSTR + i2] = v0;
            cost[i2 * RSTR + r0] = v0;
            uv0 = __float_as_uint(v0);
        }
        if (w1) {
            float d2 = q1 + qn - 2.0f * dot1;
            if (d2 < 0.f) d2 = 0.f;
            float w = (s1 * snew) / (s1 + snew + 1e-30f);
            v1 = w * d2;
            cost[r1 * RSTR + i2] = v1;
            cost[i2 * RSTR + r1] = v1;
            uv1 = __float_as_uint(v1);
        }

        // row-i2 key computed IN REGISTERS (no LDS rescan of row i2)
        {
            unsigned vm = uv0 < uv1 ? uv0 : uv1;
            int cm = (uv0 <= uv1) ? r0 : r1;  // tie -> lower col
            unsigned gm2 = wave_umin_bcast(vm);
            unsigned long long bm2 = __ballot(vm == gm2);
            int ls2 = __ffsll(bm2) - 1;
            int ccol = __builtin_amdgcn_readlane(cm, ls2);
            unsigned long long ki2 =
                ((unsigned long long)gm2 << 32) | (unsigned)((i2 << 7) | ccol);
            if (lane == (i2 >> 1)) {
                if (i2 & 1) { k1 = ki2; k1b = INVALIDK; }
                else        { k0 = ki2; k0b = INVALIDK; }
            }
        }

        // exact top-2 update per row; dirty only if min purged with no valid second
        bool dirty0 = false, dirty1 = false;
        if (w0) top2_update(k0, k0b, dirty0, v0, r0, i2, j2);
        if (w1) top2_update(k1, k1b, dirty1, v1, r1, i2, j2);
        unsigned long long mm0 = __ballot(dirty0), mm1 = __ballot(dirty1);

        // rare rescans: 2 rows/round, b128 + alive-mask + u32 half-min
        while (mm0 | mm1) {
            int rA, rB;
            bool hasB = false;
            if (mm0) { int t = __ffsll(mm0) - 1; rA = 2 * t; mm0 &= mm0 - 1; }
            else { int t = __ffsll(mm1) - 1; rA = 2 * t + 1; mm1 &= mm1 - 1; }
            if (mm0) { int t = __ffsll(mm0) - 1; rB = 2 * t; mm0 &= mm0 - 1; hasB = true; }
            else if (mm1) { int t = __ffsll(mm1) - 1; rB = 2 * t + 1; mm1 &= mm1 - 1; hasB = true; }
            else rB = rA;

            int r = (lane < 32) ? rA : rB;
            float4 cv = *(const float4*)&cost[r * RSTR + 4 * hh];
            unsigned long long word = (hh < 16) ? alive0 : alive1;
            unsigned nib = (unsigned)(word >> ((4 * hh) & 63)) & 0xFu;
            unsigned e0 = (nib & 1u) ? __float_as_uint(cv.x) : 0xFFFFFFFFu;
            unsigned e1 = (nib & 2u) ? __float_as_uint(cv.y) : 0xFFFFFFFFu;
            unsigned e2 = (nib & 4u) ? __float_as_uint(cv.z) : 0xFFFFFFFFu;
            unsigned e3 = (nib & 8u) ? __float_as_uint(cv.w) : 0xFFFFFFFFu;
            unsigned m = e0; int c = 0;
            if (e1 < m) { m = e1; c = 1; }
            if (e2 < m) { m = e2; c = 2; }
            if (e3 < m) { m = e3; c = 3; }
            int lcol = 4 * hh + c;
            unsigned hm = half_umin(m);
            unsigned vA = (unsigned)__builtin_amdgcn_readlane((int)hm, 31);
            unsigned vB = (unsigned)__builtin_amdgcn_readlane((int)hm, 63);
            unsigned vref = (lane < 32) ? vA : vB;
            unsigned long long msk = __ballot(m == vref);
            int laneA = __ffsll(msk & 0xFFFFFFFFull) - 1;
            int laneB = 32 + __ffsll(msk >> 32) - 1;
            int colA = __builtin_amdgcn_readlane(lcol, laneA);
            int colB = __builtin_amdgcn_readlane(lcol, laneB);
            unsigned long long keyA = ((unsigned long long)vA << 32) | (unsigned)((rA << 7) | colA);
            unsigned long long keyB = ((unsigned long long)vB << 32) | (unsigned)((rB << 7) | colB);
            if (lane == (rA >> 1)) { if (rA & 1) k1 = keyA; else k0 = keyA; }
            if (hasB && lane == (rB >> 1)) { if (rB & 1) k1 = keyB; else k0 = keyB; }
        }
    }

    // final relabel
    szsE[r0] = s0;
    szsE[r1] = s1;
    __asm__ volatile("s_waitcnt lgkmcnt(0)" ::: "memory");
    if (lane == 0) {
        int c = 0;
        for (int i = 0; i < NPTS; ++i) rnk[i] = (szsE[i] > 0.f) ? c++ : -1;
    }
    __asm__ volatile("s_waitcnt lgkmcnt(0)" ::: "memory");
    out[b * NPTS + r0] = rnk[lab0];
    out[b * NPTS + r1] = rnk[lab1];
}

extern "C" void kernel_launch(void* const* d_in, const int* in_sizes, int n_in,
                              void* d_out, int out_size, void* d_ws, size_t ws_size,
                              hipStream_t stream) {
    const float* x  = (const float*)d_in[0];
    const float* W1 = (const float*)d_in[1];
    const float* b1 = (const float*)d_in[2];
    const float* W2 = (const float*)d_in[3];
    const float* b2 = (const float*)d_in[4];

    float* h = (float*)d_ws;                          // 16 MB
    float* feats = h + (size_t)MROWS * H1;            // 2 MB
    float* gx = feats + (size_t)MROWS * DOUT;         // 64 MB (if it fits)
    int* out = (int*)d_out;

    const size_t need = ((size_t)MROWS * H1 + (size_t)MROWS * DOUT + (size_t)MROWS * DIN) * 4;
    const bool use_gx = ws_size >= need;

    if (use_gx) {
        gelu_kernel<<<2048, 256, 0, stream>>>(x, gx, MROWS * DIN / 4);
        mlp1_kernel<false><<<dim3(MROWS / 128, H1 / 128), 256, 0, stream>>>(gx, W1, b1, h);
    } else {
        mlp1_kernel<true><<<dim3(MROWS / 128, H1 / 128), 256, 0, stream>>>(x, W1, b1, h);
    }
    mlp2_kernel<<<MROWS / 16, 256, 0, stream>>>(h, W2, b2, feats);
    ward_kernel<<<BB, 256, 0, stream>>>(feats, out);
}

// Round 3
// 489.230 us; speedup vs baseline: 1.0266x; 1.0266x over previous
//
#include <hip/hip_runtime.h>
#include <math.h>

#define BB 128
#define NN 128
#define DIN 1024
#define H1 256
#define DOUT 32
#define KCL 8
#define NPTS 128
#define MROWS (BB*NN)   // 16384
#define CSTR 130        // centsT row stride (words, init staging only)
#define RSTR 132        // cost/G row stride (words, 16B aligned)
#define DEADKEY 0xFFFFFFFF00000000ull

__device__ __forceinline__ float gelu_exact(float v) {
    return 0.5f * v * (1.0f + erff(v * 0.70710678118654752f));
}

__device__ __forceinline__ unsigned long long mkkey(float v, int r, int j) {
    return ((unsigned long long)__float_as_uint(v) << 32) | (unsigned)((r << 7) | j);
}

__device__ __forceinline__ float readlanef(float v, int lane) {
    return __int_as_float(__builtin_amdgcn_readlane(__float_as_int(v), lane));
}

// u32 min via DPP (costs are >=0 floats: IEEE order == unsigned bit order)
template<int CTRL, int RMASK>
__device__ __forceinline__ unsigned dpp_umin_step(unsigned v) {
    unsigned t = (unsigned)__builtin_amdgcn_update_dpp((int)v, (int)v, CTRL, RMASK, 0xf, false);
    return t < v ? t : v;
}
__device__ __forceinline__ unsigned wave_umin_bcast(unsigned v) {
    v = dpp_umin_step<0x111, 0xf>(v);
    v = dpp_umin_step<0x112, 0xf>(v);
    v = dpp_umin_step<0x114, 0xf>(v);
    v = dpp_umin_step<0x118, 0xf>(v);
    v = dpp_umin_step<0x142, 0xa>(v);
    v = dpp_umin_step<0x143, 0xc>(v);
    return (unsigned)__builtin_amdgcn_readlane((int)v, 63);
}
// lane31 = min(lanes0..31), lane63 = min(lanes32..63)
__device__ __forceinline__ unsigned half_umin(unsigned v) {
    v = dpp_umin_step<0x111, 0xf>(v);
    v = dpp_umin_step<0x112, 0xf>(v);
    v = dpp_umin_step<0x114, 0xf>(v);
    v = dpp_umin_step<0x118, 0xf>(v);
    v = dpp_umin_step<0x142, 0xa>(v);
    return v;
}

// ---------------- gelu precompute: gx = gelu(x), memory-bound ----------------
__global__ __launch_bounds__(256) void gelu_kernel(const float* __restrict__ x,
                                                   float* __restrict__ gx, int n4) {
    int i = blockIdx.x * 256 + threadIdx.x;
    const int stride = gridDim.x * 256;
    for (; i < n4; i += stride) {
        float4 v = ((const float4*)x)[i];
        v.x = gelu_exact(v.x);
        v.y = gelu_exact(v.y);
        v.z = gelu_exact(v.z);
        v.w = gelu_exact(v.w);
        ((float4*)gx)[i] = v;
    }
}

// ---------------- GEMM1: h = A @ W1 + b1 ----------------
// 128x64 tile, 8x4 microtile, BK=16, double-buffered LDS, grid (128,4)=512 blocks = 2/CU.
// FUSE=true: A = gelu(x) applied at staging (fallback). FUSE=false: A = gx (pre-gelu'd).
template<bool FUSE>
__global__ __launch_bounds__(256) void mlp1_kernel(const float* __restrict__ xin,
                                                   const float* __restrict__ W1,
                                                   const float* __restrict__ b1,
                                                   float* __restrict__ h) {
    __shared__ float As[2][16][132];  // [buf][k][m] 16.9 KB
    __shared__ float Bs[2][16][68];   // [buf][k][n]  8.7 KB
    const int bm = blockIdx.x;        // 128 row-tiles of 128
    const int bn = blockIdx.y;        // 4 col-tiles of 64
    const int tid = threadIdx.x;
    const int tx = tid & 15;          // col quad 0..15
    const int ty = tid >> 4;          // row quad 0..15

    float acc[8][4];
#pragma unroll
    for (int i = 0; i < 8; ++i)
#pragma unroll
        for (int j = 0; j < 4; ++j) acc[i][j] = 0.f;

    const int arow = tid >> 1;        // 0..127
    const int ak8  = (tid & 1) * 8;   // 0 or 8
    const int bk   = tid >> 4;        // 0..15
    const int bcol = (tid & 15) * 4;  // 0..60

    const float* xrow = xin + (size_t)(bm * 128 + arow) * DIN;
    const float* wbase = W1 + bn * 64;

    // prologue: load tile 0, stage to buf 0
    float4 a0 = *(const float4*)(xrow + ak8);
    float4 a1 = *(const float4*)(xrow + ak8 + 4);
    float4 w0 = *(const float4*)(wbase + (size_t)bk * H1 + bcol);
    if (FUSE) {
        As[0][ak8 + 0][arow] = gelu_exact(a0.x);
        As[0][ak8 + 1][arow] = gelu_exact(a0.y);
        As[0][ak8 + 2][arow] = gelu_exact(a0.z);
        As[0][ak8 + 3][arow] = gelu_exact(a0.w);
        As[0][ak8 + 4][arow] = gelu_exact(a1.x);
        As[0][ak8 + 5][arow] = gelu_exact(a1.y);
        As[0][ak8 + 6][arow] = gelu_exact(a1.z);
        As[0][ak8 + 7][arow] = gelu_exact(a1.w);
    } else {
        As[0][ak8 + 0][arow] = a0.x;
        As[0][ak8 + 1][arow] = a0.y;
        As[0][ak8 + 2][arow] = a0.z;
        As[0][ak8 + 3][arow] = a0.w;
        As[0][ak8 + 4][arow] = a1.x;
        As[0][ak8 + 5][arow] = a1.y;
        As[0][ak8 + 6][arow] = a1.z;
        As[0][ak8 + 7][arow] = a1.w;
    }
    *(float4*)&Bs[0][bk][bcol] = w0;
    __syncthreads();

    int cur = 0;
    for (int kt = 0; kt < DIN; kt += 16) {
        const bool has_next = (kt + 16) < DIN;
        if (has_next) {  // issue next-tile loads; latency hidden under the FMA block
            a0 = *(const float4*)(xrow + kt + 16 + ak8);
            a1 = *(const float4*)(xrow + kt + 16 + ak8 + 4);
            w0 = *(const float4*)(wbase + (size_t)(kt + 16 + bk) * H1 + bcol);
        }
#pragma unroll
        for (int kk = 0; kk < 16; ++kk) {
            float4 aL = *(const float4*)&As[cur][kk][ty * 4];
            float4 aH = *(const float4*)&As[cur][kk][64 + ty * 4];
            float4 bv = *(const float4*)&Bs[cur][kk][tx * 4];
            float ar[8] = {aL.x, aL.y, aL.z, aL.w, aH.x, aH.y, aH.z, aH.w};
            float br[4] = {bv.x, bv.y, bv.z, bv.w};
#pragma unroll
            for (int i = 0; i < 8; ++i)
#pragma unroll
                for (int j = 0; j < 4; ++j)
                    acc[i][j] = fmaf(ar[i], br[j], acc[i][j]);
        }
        if (has_next) {
            const int nxt = cur ^ 1;
            if (FUSE) {
                As[nxt][ak8 + 0][arow] = gelu_exact(a0.x);
                As[nxt][ak8 + 1][arow] = gelu_exact(a0.y);
                As[nxt][ak8 + 2][arow] = gelu_exact(a0.z);
                As[nxt][ak8 + 3][arow] = gelu_exact(a0.w);
                As[nxt][ak8 + 4][arow] = gelu_exact(a1.x);
                As[nxt][ak8 + 5][arow] = gelu_exact(a1.y);
                As[nxt][ak8 + 6][arow] = gelu_exact(a1.z);
                As[nxt][ak8 + 7][arow] = gelu_exact(a1.w);
            } else {
                As[nxt][ak8 + 0][arow] = a0.x;
                As[nxt][ak8 + 1][arow] = a0.y;
                As[nxt][ak8 + 2][arow] = a0.z;
                As[nxt][ak8 + 3][arow] = a0.w;
                As[nxt][ak8 + 4][arow] = a1.x;
                As[nxt][ak8 + 5][arow] = a1.y;
                As[nxt][ak8 + 6][arow] = a1.z;
                As[nxt][ak8 + 7][arow] = a1.w;
            }
            *(float4*)&Bs[nxt][bk][bcol] = w0;
        }
        __syncthreads();
        cur ^= 1;
    }

    const int row0 = bm * 128 + ty * 4;
    const int col0 = bn * 64 + tx * 4;
    float4 bias = *(const float4*)(b1 + col0);
#pragma unroll
    for (int i = 0; i < 8; ++i) {
        const int rr = (i < 4) ? i : (64 + i - 4);
        float4 o;
        o.x = acc[i][0] + bias.x;
        o.y = acc[i][1] + bias.y;
        o.z = acc[i][2] + bias.z;
        o.w = acc[i][3] + bias.w;
        *(float4*)(h + (size_t)(row0 + rr) * H1 + col0) = o;
    }
}

// ---------------- GEMM2: feats = gelu(h) @ W2 + b2 (best-measured R4 version) ----------------
__global__ __launch_bounds__(256) void mlp2_kernel(const float* __restrict__ h,
                                                   const float* __restrict__ W2,
                                                   const float* __restrict__ b2,
                                                   float* __restrict__ feats) {
    __shared__ float hs[16][257];
    __shared__ float w2s[H1 * DOUT];
    const int blk = blockIdx.x;
    const int tid = threadIdx.x;

    for (int i = tid; i < (H1 * DOUT) / 4; i += 256) {
        ((float4*)w2s)[i] = ((const float4*)W2)[i];
    }
    const float* hb = h + (size_t)blk * 16 * H1;
    for (int i = tid; i < (16 * H1) / 4; i += 256) {
        float4 v = ((const float4*)hb)[i];
        int r = i >> 6;
        int c = (i & 63) * 4;
        hs[r][c + 0] = gelu_exact(v.x);
        hs[r][c + 1] = gelu_exact(v.y);
        hs[r][c + 2] = gelu_exact(v.z);
        hs[r][c + 3] = gelu_exact(v.w);
    }
    __syncthreads();

    const int col = tid & 31;
    const int r0 = (tid >> 5) * 2;
    float acc0 = 0.f, acc1 = 0.f;
    for (int k = 0; k < H1; ++k) {
        float w = w2s[k * DOUT + col];
        acc0 = fmaf(hs[r0 + 0][k], w, acc0);
        acc1 = fmaf(hs[r0 + 1][k], w, acc1);
    }
    float bias = b2[col];
    const int rowg = blk * 16 + r0;
    feats[(size_t)(rowg + 0) * DOUT + col] = acc0 + bias;
    feats[(size_t)(rowg + 1) * DOUT + col] = acc1 + bias;
}

// ---------------- Ward clustering: incremental Gram, i2 folded into rescan loop ----------------
__global__ __launch_bounds__(256) void ward_kernel(const float* __restrict__ feats,
                                                   int* __restrict__ out) {
    __shared__ __align__(16) float cost[NPTS * RSTR];  // 67.6 KB
    __shared__ __align__(16) float G[NPTS * RSTR];     // 67.6 KB Gram matrix
    __shared__ float centsT[32 * CSTR];                // init staging only
    __shared__ unsigned long long rowkey[NPTS];
    __shared__ float sqArr[NPTS];
    __shared__ float szsE[NPTS];
    __shared__ int rnk[NPTS];

    const int b = blockIdx.x;
    const int tid = threadIdx.x;
    const float* f = feats + (size_t)b * NPTS * DOUT;
    const float INF = __builtin_inff();

    // ---- init (all 4 waves) ----
    for (int i = tid; i < NPTS * DOUT; i += 256) {
        int r = i >> 5, d = i & 31;
        centsT[d * CSTR + r] = f[i];
    }
    __syncthreads();
    if (tid < NPTS) {
        float s = 0.f;
#pragma unroll
        for (int d = 0; d < 32; ++d) {
            float v = centsT[d * CSTR + tid];
            s = fmaf(v, v, s);
        }
        sqArr[tid] = s;
    }
    __syncthreads();
    {
        int ti = tid >> 4, tj = tid & 15;
        int I0 = ti * 8, J0 = tj * 8;
        float acc[8][8];
#pragma unroll
        for (int u = 0; u < 8; ++u)
#pragma unroll
            for (int v = 0; v < 8; ++v) acc[u][v] = 0.f;
        for (int d = 0; d < 32; ++d) {
            float a[8], bb[8];
#pragma unroll
            for (int u = 0; u < 8; ++u) a[u] = centsT[d * CSTR + I0 + u];
#pragma unroll
            for (int v = 0; v < 8; ++v) bb[v] = centsT[d * CSTR + J0 + v];
#pragma unroll
            for (int u = 0; u < 8; ++u)
#pragma unroll
                for (int v = 0; v < 8; ++v)
                    acc[u][v] = fmaf(a[u], bb[v], acc[u][v]);
        }
#pragma unroll
        for (int u = 0; u < 8; ++u) {
#pragma unroll
            for (int v = 0; v < 8; ++v) {
                int i = I0 + u, j = J0 + v;
                G[i * RSTR + j] = acc[u][v];
                float d2 = sqArr[i] + sqArr[j] - 2.0f * acc[u][v];
                if (d2 < 0.f) d2 = 0.f;
                float w = (1.0f * 1.0f) / (1.0f + 1.0f + 1e-30f);
                cost[i * RSTR + j] = (i == j) ? INF : w * d2;
            }
        }
    }
    __syncthreads();
    if (tid < NPTS) {
        unsigned long long best = DEADKEY;
        for (int j = 0; j < NPTS; ++j) {
            float v = cost[tid * RSTR + j];
            unsigned long long k = mkkey(v, tid, j);
            if (k < best) best = k;
        }
        rowkey[tid] = best;
    }
    __syncthreads();

    if (tid >= 64) return;  // wave 0 only
    const int lane = tid;
    const int hh = lane & 31;
    const int r0 = lane * 2, r1 = lane * 2 + 1;

    unsigned long long k0 = rowkey[r0], k1 = rowkey[r1];
    float q0 = sqArr[r0], q1 = sqArr[r1];
    float s0 = 1.0f, s1 = 1.0f;
    int lab0 = r0, lab1 = r1;
    unsigned long long alive0 = ~0ull, alive1 = ~0ull;

    for (int it = 0; it < NPTS - KCL; ++it) {
        // P1: global argmin via u32-bits DPP min + ballot (exact flat-index tie-break)
        unsigned bv0 = (unsigned)(k0 >> 32), bv1 = (unsigned)(k1 >> 32);
        unsigned lmin = bv0 < bv1 ? bv0 : bv1;
        unsigned lflat = (bv0 <= bv1) ? (unsigned)(k0 & 0x3FFFu) : (unsigned)(k1 & 0x3FFFu);
        unsigned gmin = wave_umin_bcast(lmin);
        unsigned long long bmask = __ballot(lmin == gmin);
        int lsel = __ffsll(bmask) - 1;
        unsigned flat = (unsigned)__builtin_amdgcn_readlane((int)lflat, lsel);
        int ra = (int)(flat >> 7), ca = (int)(flat & 127u);
        const int i2 = ra < ca ? ra : ca;
        const int j2 = ra < ca ? ca : ra;

        // Gram rows i2, j2 (issued early; only depend on i2/j2)
        float2 gi = *(const float2*)&G[i2 * RSTR + r0];
        float2 gj = *(const float2*)&G[j2 * RSTR + r0];

        float si = readlanef((i2 & 1) ? s1 : s0, i2 >> 1);
        float sj = readlanef((j2 & 1) ? s1 : s0, j2 >> 1);
        const float snew = si + sj;
        const float invs = 1.0f / snew;
        const float wa = si * invs, wb = sj * invs;

        int arg0 = (int)(k0 & 127u), arg1 = (int)(k1 & 127u);
        bool d0 = (s0 > 0.f) && r0 != i2 && r0 != j2 && (arg0 == i2 || arg0 == j2);
        bool d1 = (s1 > 0.f) && r1 != i2 && r1 != j2 && (arg1 == i2 || arg1 == j2);
        unsigned long long m0 = __ballot(d0), m1 = __ballot(d1);

        // scalar Gram entries for qn
        float Gii = readlanef((i2 & 1) ? gi.y : gi.x, i2 >> 1);
        float Gij = readlanef((i2 & 1) ? gj.y : gj.x, i2 >> 1);
        float Gjj = readlanef((j2 & 1) ? gj.y : gj.x, j2 >> 1);
        float dotA = wa * Gii + wb * Gij;
        float dotB = wa * Gij + wb * Gjj;
        float qn = wa * dotA + wb * dotB;

        // per-lane dots with merged cluster (linear Gram update)
        float dot0 = wa * gi.x + wb * gj.x;
        float dot1 = wa * gi.y + wb * gj.y;

        // state updates
        if (lab0 == j2) lab0 = i2;
        if (lab1 == j2) lab1 = i2;
        if (r0 == i2) s0 = snew; else if (r0 == j2) { s0 = 0.f; k0 = DEADKEY; }
        if (r1 == i2) s1 = snew; else if (r1 == j2) { s1 = 0.f; k1 = DEADKEY; }
        if (j2 < 64) alive0 &= ~(1ull << j2); else alive1 &= ~(1ull << (j2 - 64));
        if (r0 == i2) { dot0 = qn; q0 = qn; }
        if (r1 == i2) { dot1 = qn; q1 = qn; }

        // G updates: row i2 (contiguous b64), column i2
        *(float2*)&G[i2 * RSTR + r0] = make_float2(dot0, dot1);
        G[r0 * RSTR + i2] = dot0;
        G[r1 * RSTR + i2] = dot1;

        // cost values for row/col i2
        bool w0 = (s0 > 0.f) && r0 != i2 && r0 != j2;
        bool w1 = (s1 > 0.f) && r1 != i2 && r1 != j2;
        if (w0) {
            float d2 = q0 + qn - 2.0f * dot0;
            if (d2 < 0.f) d2 = 0.f;
            float w = (s0 * snew) / (s0 + snew + 1e-30f);
            float v0 = w * d2;
            cost[r0 * RSTR + i2] = v0;
            cost[i2 * RSTR + r0] = v0;
            if (!d0) {
                unsigned long long nk = mkkey(v0, r0, i2);
                if (nk < k0) k0 = nk;
            }
        }
        if (w1) {
            float d2 = q1 + qn - 2.0f * dot1;
            if (d2 < 0.f) d2 = 0.f;
            float w = (s1 * snew) / (s1 + snew + 1e-30f);
            float v1 = w * d2;
            cost[r1 * RSTR + i2] = v1;
            cost[i2 * RSTR + r1] = v1;
            if (!d1) {
                unsigned long long nk = mkkey(v1, r1, i2);
                if (nk < k1) k1 = nk;
            }
        }

        // rescans: row i2 (always) + dirty rows; 2 rows/round, b128 + alive-mask + u32 half-min
        bool pi = true;
        unsigned long long mm0 = m0, mm1 = m1;
        while (pi | (mm0 != 0ull) | (mm1 != 0ull)) {
            int rA, rB;
            bool hasB = false;
            if (pi) { rA = i2; pi = false; }
            else if (mm0) { int t = __ffsll(mm0) - 1; rA = 2 * t; mm0 &= mm0 - 1; }
            else { int t = __ffsll(mm1) - 1; rA = 2 * t + 1; mm1 &= mm1 - 1; }
            if (mm0) { int t = __ffsll(mm0) - 1; rB = 2 * t; mm0 &= mm0 - 1; hasB = true; }
            else if (mm1) { int t = __ffsll(mm1) - 1; rB = 2 * t + 1; mm1 &= mm1 - 1; hasB = true; }
            else rB = rA;

            int r = (lane < 32) ? rA : rB;
            float4 cv = *(const float4*)&cost[r * RSTR + 4 * hh];
            unsigned long long word = (hh < 16) ? alive0 : alive1;
            unsigned nib = (unsigned)(word >> ((4 * hh) & 63)) & 0xFu;
            unsigned e0 = (nib & 1u) ? __float_as_uint(cv.x) : 0xFFFFFFFFu;
            unsigned e1 = (nib & 2u) ? __float_as_uint(cv.y) : 0xFFFFFFFFu;
            unsigned e2 = (nib & 4u) ? __float_as_uint(cv.z) : 0xFFFFFFFFu;
            unsigned e3 = (nib & 8u) ? __float_as_uint(cv.w) : 0xFFFFFFFFu;
            unsigned m = e0; int c = 0;
            if (e1 < m) { m = e1; c = 1; }
            if (e2 < m) { m = e2; c = 2; }
            if (e3 < m) { m = e3; c = 3; }
            int lcol = 4 * hh + c;
            unsigned hm = half_umin(m);
            unsigned vA = (unsigned)__builtin_amdgcn_readlane((int)hm, 31);
            unsigned vB = (unsigned)__builtin_amdgcn_readlane((int)hm, 63);
            unsigned vref = (lane < 32) ? vA : vB;
            unsigned long long msk = __ballot(m == vref);
            int laneA = __ffsll(msk & 0xFFFFFFFFull) - 1;
            int laneB = 32 + __ffsll(msk >> 32) - 1;
            int colA = __builtin_amdgcn_readlane(lcol, laneA);
            int colB = __builtin_amdgcn_readlane(lcol, laneB);
            unsigned long long keyA = ((unsigned long long)vA << 32) | (unsigned)((rA << 7) | colA);
            unsigned long long keyB = ((unsigned long long)vB << 32) | (unsigned)((rB << 7) | colB);
            if (lane == (rA >> 1)) { if (rA & 1) k1 = keyA; else k0 = keyA; }
            if (hasB && lane == (rB >> 1)) { if (rB & 1) k1 = keyB; else k0 = keyB; }
        }
    }

    // final relabel
    szsE[r0] = s0;
    szsE[r1] = s1;
    __asm__ volatile("s_waitcnt lgkmcnt(0)" ::: "memory");
    if (lane == 0) {
        int c = 0;
        for (int i = 0; i < NPTS; ++i) rnk[i] = (szsE[i] > 0.f) ? c++ : -1;
    }
    __asm__ volatile("s_waitcnt lgkmcnt(0)" ::: "memory");
    out[b * NPTS + r0] = rnk[lab0];
    out[b * NPTS + r1] = rnk[lab1];
}

extern "C" void kernel_launch(void* const* d_in, const int* in_sizes, int n_in,
                              void* d_out, int out_size, void* d_ws, size_t ws_size,
                              hipStream_t stream) {
    const float* x  = (const float*)d_in[0];
    const float* W1 = (const float*)d_in[1];
    const float* b1 = (const float*)d_in[2];
    const float* W2 = (const float*)d_in[3];
    const float* b2 = (const float*)d_in[4];

    float* h = (float*)d_ws;                          // 16 MB
    float* feats = h + (size_t)MROWS * H1;            // 2 MB
    float* gx = feats + (size_t)MROWS * DOUT;         // 64 MB (if it fits)
    int* out = (int*)d_out;

    const size_t need = ((size_t)MROWS * H1 + (size_t)MROWS * DOUT + (size_t)MROWS * DIN) * 4;
    const bool use_gx = ws_size >= need;

    if (use_gx) {
        gelu_kernel<<<2048, 256, 0, stream>>>(x, gx, MROWS * DIN / 4);
        mlp1_kernel<false><<<dim3(MROWS / 128, H1 / 64), 256, 0, stream>>>(gx, W1, b1, h);
    } else {
        mlp1_kernel<true><<<dim3(MROWS / 128, H1 / 64), 256, 0, stream>>>(x, W1, b1, h);
    }
    mlp2_kernel<<<MROWS / 16, 256, 0, stream>>>(h, W2, b2, feats);
    ward_kernel<<<BB, 256, 0, stream>>>(feats, out);
}

// Round 4
// 444.092 us; speedup vs baseline: 1.1310x; 1.1016x over previous
//
#include <hip/hip_runtime.h>
#include <math.h>

#define BB 128
#define NN 128
#define DIN 1024
#define H1 256
#define DOUT 32
#define KCL 8
#define NPTS 128
#define MROWS (BB*NN)   // 16384
#define CSTR 130        // centsT row stride (words, init staging only)
#define RSTR 132        // cost/G row stride (words, 16B aligned)
#define DEADKEY 0xFFFFFFFF00000000ull

__device__ __forceinline__ float gelu_exact(float v) {
    return 0.5f * v * (1.0f + erff(v * 0.70710678118654752f));
}

__device__ __forceinline__ unsigned long long mkkey(float v, int r, int j) {
    return ((unsigned long long)__float_as_uint(v) << 32) | (unsigned)((r << 7) | j);
}

__device__ __forceinline__ float readlanef(float v, int lane) {
    return __int_as_float(__builtin_amdgcn_readlane(__float_as_int(v), lane));
}

// u32 min via DPP (costs are >=0 floats: IEEE order == unsigned bit order)
template<int CTRL, int RMASK>
__device__ __forceinline__ unsigned dpp_umin_step(unsigned v) {
    unsigned t = (unsigned)__builtin_amdgcn_update_dpp((int)v, (int)v, CTRL, RMASK, 0xf, false);
    return t < v ? t : v;
}
__device__ __forceinline__ unsigned wave_umin_bcast(unsigned v) {
    v = dpp_umin_step<0x111, 0xf>(v);
    v = dpp_umin_step<0x112, 0xf>(v);
    v = dpp_umin_step<0x114, 0xf>(v);
    v = dpp_umin_step<0x118, 0xf>(v);
    v = dpp_umin_step<0x142, 0xa>(v);
    v = dpp_umin_step<0x143, 0xc>(v);
    return (unsigned)__builtin_amdgcn_readlane((int)v, 63);
}
// lane31 = min(lanes0..31), lane63 = min(lanes32..63)
__device__ __forceinline__ unsigned half_umin(unsigned v) {
    v = dpp_umin_step<0x111, 0xf>(v);
    v = dpp_umin_step<0x112, 0xf>(v);
    v = dpp_umin_step<0x114, 0xf>(v);
    v = dpp_umin_step<0x118, 0xf>(v);
    v = dpp_umin_step<0x142, 0xa>(v);
    return v;
}

// ---------------- GEMM1: h = gelu(x) @ W1 + b1 ; R0 structure (64x64, BK=32, grid 1024) ----------------
// gelu fused at staging: mlp1 is LDS-BW-bound (2.0 B/FMA), so the erf VALU work hides
// under the LDS ceiling; kills the standalone gelu kernel + 128 MB of HBM traffic.
__global__ __launch_bounds__(256) void mlp1_kernel(const float* __restrict__ xin,
                                                   const float* __restrict__ W1,
                                                   const float* __restrict__ b1,
                                                   float* __restrict__ h) {
    __shared__ float As[32][68];  // [k][m]
    __shared__ float Bs[32][68];  // [k][n]
    const int bm = blockIdx.x;    // 256 row-tiles of 64
    const int bn = blockIdx.y;    // 4 col-tiles of 64
    const int tid = threadIdx.x;
    const int tx = tid & 15, ty = tid >> 4;

    float acc[4][4] = {{0.f}};

    const int arow = tid >> 2;         // 0..63
    const int acol4 = (tid & 3) * 4;   // k offset 0,4,8,12
    const int brow = tid >> 4;         // 0..15 (k)
    const int bcol4 = (tid & 15) * 4;  // 0..60

    const float* xrow = xin + (size_t)(bm * 64 + arow) * DIN;
    const float* wbase = W1 + bn * 64;

    for (int kt = 0; kt < DIN; kt += 32) {
        float4 a0 = *(const float4*)(xrow + kt + acol4);
        float4 a1 = *(const float4*)(xrow + kt + 16 + acol4);
        float4 w0 = *(const float4*)(wbase + (size_t)(kt + brow) * H1 + bcol4);
        float4 w1 = *(const float4*)(wbase + (size_t)(kt + 16 + brow) * H1 + bcol4);
        __syncthreads();
        As[acol4 + 0][arow] = gelu_exact(a0.x);
        As[acol4 + 1][arow] = gelu_exact(a0.y);
        As[acol4 + 2][arow] = gelu_exact(a0.z);
        As[acol4 + 3][arow] = gelu_exact(a0.w);
        As[16 + acol4 + 0][arow] = gelu_exact(a1.x);
        As[16 + acol4 + 1][arow] = gelu_exact(a1.y);
        As[16 + acol4 + 2][arow] = gelu_exact(a1.z);
        As[16 + acol4 + 3][arow] = gelu_exact(a1.w);
        *(float4*)&Bs[brow][bcol4] = w0;
        *(float4*)&Bs[16 + brow][bcol4] = w1;
        __syncthreads();
#pragma unroll
        for (int kk = 0; kk < 32; ++kk) {
            float4 a = *(const float4*)&As[kk][ty * 4];
            float4 b = *(const float4*)&Bs[kk][tx * 4];
            float ar[4] = {a.x, a.y, a.z, a.w};
            float br[4] = {b.x, b.y, b.z, b.w};
#pragma unroll
            for (int i = 0; i < 4; ++i)
#pragma unroll
                for (int j = 0; j < 4; ++j)
                    acc[i][j] = fmaf(ar[i], br[j], acc[i][j]);
        }
    }

    const int row = bm * 64 + ty * 4;
    const int col = bn * 64 + tx * 4;
    float4 bias = *(const float4*)(b1 + col);
#pragma unroll
    for (int i = 0; i < 4; ++i) {
        float4 o;
        o.x = acc[i][0] + bias.x;
        o.y = acc[i][1] + bias.y;
        o.z = acc[i][2] + bias.z;
        o.w = acc[i][3] + bias.w;
        *(float4*)(h + (size_t)(row + i) * H1 + col) = o;
    }
}

// ---------------- GEMM2: feats = gelu(h) @ W2 + b2 (best-measured R4 version) ----------------
__global__ __launch_bounds__(256) void mlp2_kernel(const float* __restrict__ h,
                                                   const float* __restrict__ W2,
                                                   const float* __restrict__ b2,
                                                   float* __restrict__ feats) {
    __shared__ float hs[16][257];
    __shared__ float w2s[H1 * DOUT];
    const int blk = blockIdx.x;
    const int tid = threadIdx.x;

    for (int i = tid; i < (H1 * DOUT) / 4; i += 256) {
        ((float4*)w2s)[i] = ((const float4*)W2)[i];
    }
    const float* hb = h + (size_t)blk * 16 * H1;
    for (int i = tid; i < (16 * H1) / 4; i += 256) {
        float4 v = ((const float4*)hb)[i];
        int r = i >> 6;
        int c = (i & 63) * 4;
        hs[r][c + 0] = gelu_exact(v.x);
        hs[r][c + 1] = gelu_exact(v.y);
        hs[r][c + 2] = gelu_exact(v.z);
        hs[r][c + 3] = gelu_exact(v.w);
    }
    __syncthreads();

    const int col = tid & 31;
    const int r0 = (tid >> 5) * 2;
    float acc0 = 0.f, acc1 = 0.f;
    for (int k = 0; k < H1; ++k) {
        float w = w2s[k * DOUT + col];
        acc0 = fmaf(hs[r0 + 0][k], w, acc0);
        acc1 = fmaf(hs[r0 + 1][k], w, acc1);
    }
    float bias = b2[col];
    const int rowg = blk * 16 + r0;
    feats[(size_t)(rowg + 0) * DOUT + col] = acc0 + bias;
    feats[(size_t)(rowg + 1) * DOUT + col] = acc1 + bias;
}

// ---------------- Ward clustering: incremental Gram, i2 folded into rescan loop ----------------
__global__ __launch_bounds__(256) void ward_kernel(const float* __restrict__ feats,
                                                   int* __restrict__ out) {
    __shared__ __align__(16) float cost[NPTS * RSTR];  // 67.6 KB
    __shared__ __align__(16) float G[NPTS * RSTR];     // 67.6 KB Gram matrix
    __shared__ float centsT[32 * CSTR];                // init staging only
    __shared__ unsigned long long rowkey[NPTS];
    __shared__ float sqArr[NPTS];
    __shared__ float szsE[NPTS];
    __shared__ int rnk[NPTS];

    const int b = blockIdx.x;
    const int tid = threadIdx.x;
    const float* f = feats + (size_t)b * NPTS * DOUT;
    const float INF = __builtin_inff();

    // ---- init (all 4 waves) ----
    for (int i = tid; i < NPTS * DOUT; i += 256) {
        int r = i >> 5, d = i & 31;
        centsT[d * CSTR + r] = f[i];
    }
    __syncthreads();
    if (tid < NPTS) {
        float s = 0.f;
#pragma unroll
        for (int d = 0; d < 32; ++d) {
            float v = centsT[d * CSTR + tid];
            s = fmaf(v, v, s);
        }
        sqArr[tid] = s;
    }
    __syncthreads();
    {
        int ti = tid >> 4, tj = tid & 15;
        int I0 = ti * 8, J0 = tj * 8;
        float acc[8][8];
#pragma unroll
        for (int u = 0; u < 8; ++u)
#pragma unroll
            for (int v = 0; v < 8; ++v) acc[u][v] = 0.f;
        for (int d = 0; d < 32; ++d) {
            float a[8], bb[8];
#pragma unroll
            for (int u = 0; u < 8; ++u) a[u] = centsT[d * CSTR + I0 + u];
#pragma unroll
            for (int v = 0; v < 8; ++v) bb[v] = centsT[d * CSTR + J0 + v];
#pragma unroll
            for (int u = 0; u < 8; ++u)
#pragma unroll
                for (int v = 0; v < 8; ++v)
                    acc[u][v] = fmaf(a[u], bb[v], acc[u][v]);
        }
#pragma unroll
        for (int u = 0; u < 8; ++u) {
#pragma unroll
            for (int v = 0; v < 8; ++v) {
                int i = I0 + u, j = J0 + v;
                G[i * RSTR + j] = acc[u][v];
                float d2 = sqArr[i] + sqArr[j] - 2.0f * acc[u][v];
                if (d2 < 0.f) d2 = 0.f;
                float w = (1.0f * 1.0f) / (1.0f + 1.0f + 1e-30f);
                cost[i * RSTR + j] = (i == j) ? INF : w * d2;
            }
        }
    }
    __syncthreads();
    if (tid < NPTS) {
        unsigned long long best = DEADKEY;
        for (int j = 0; j < NPTS; ++j) {
            float v = cost[tid * RSTR + j];
            unsigned long long k = mkkey(v, tid, j);
            if (k < best) best = k;
        }
        rowkey[tid] = best;
    }
    __syncthreads();

    if (tid >= 64) return;  // wave 0 only
    const int lane = tid;
    const int hh = lane & 31;
    const int r0 = lane * 2, r1 = lane * 2 + 1;

    unsigned long long k0 = rowkey[r0], k1 = rowkey[r1];
    float q0 = sqArr[r0], q1 = sqArr[r1];
    float s0 = 1.0f, s1 = 1.0f;
    int lab0 = r0, lab1 = r1;
    unsigned long long alive0 = ~0ull, alive1 = ~0ull;

    for (int it = 0; it < NPTS - KCL; ++it) {
        // P1: global argmin via u32-bits DPP min + ballot (exact flat-index tie-break)
        unsigned bv0 = (unsigned)(k0 >> 32), bv1 = (unsigned)(k1 >> 32);
        unsigned lmin = bv0 < bv1 ? bv0 : bv1;
        unsigned lflat = (bv0 <= bv1) ? (unsigned)(k0 & 0x3FFFu) : (unsigned)(k1 & 0x3FFFu);
        unsigned gmin = wave_umin_bcast(lmin);
        unsigned long long bmask = __ballot(lmin == gmin);
        int lsel = __ffsll(bmask) - 1;
        unsigned flat = (unsigned)__builtin_amdgcn_readlane((int)lflat, lsel);
        int ra = (int)(flat >> 7), ca = (int)(flat & 127u);
        const int i2 = ra < ca ? ra : ca;
        const int j2 = ra < ca ? ca : ra;

        // Gram rows i2, j2 (issued early; only depend on i2/j2)
        float2 gi = *(const float2*)&G[i2 * RSTR + r0];
        float2 gj = *(const float2*)&G[j2 * RSTR + r0];

        float si = readlanef((i2 & 1) ? s1 : s0, i2 >> 1);
        float sj = readlanef((j2 & 1) ? s1 : s0, j2 >> 1);
        const float snew = si + sj;
        const float invs = 1.0f / snew;
        const float wa = si * invs, wb = sj * invs;

        int arg0 = (int)(k0 & 127u), arg1 = (int)(k1 & 127u);
        bool d0 = (s0 > 0.f) && r0 != i2 && r0 != j2 && (arg0 == i2 || arg0 == j2);
        bool d1 = (s1 > 0.f) && r1 != i2 && r1 != j2 && (arg1 == i2 || arg1 == j2);
        unsigned long long m0 = __ballot(d0), m1 = __ballot(d1);

        // scalar Gram entries for qn
        float Gii = readlanef((i2 & 1) ? gi.y : gi.x, i2 >> 1);
        float Gij = readlanef((i2 & 1) ? gj.y : gj.x, i2 >> 1);
        float Gjj = readlanef((j2 & 1) ? gj.y : gj.x, j2 >> 1);
        float dotA = wa * Gii + wb * Gij;
        float dotB = wa * Gij + wb * Gjj;
        float qn = wa * dotA + wb * dotB;

        // per-lane dots with merged cluster (linear Gram update)
        float dot0 = wa * gi.x + wb * gj.x;
        float dot1 = wa * gi.y + wb * gj.y;

        // state updates
        if (lab0 == j2) lab0 = i2;
        if (lab1 == j2) lab1 = i2;
        if (r0 == i2) s0 = snew; else if (r0 == j2) { s0 = 0.f; k0 = DEADKEY; }
        if (r1 == i2) s1 = snew; else if (r1 == j2) { s1 = 0.f; k1 = DEADKEY; }
        if (j2 < 64) alive0 &= ~(1ull << j2); else alive1 &= ~(1ull << (j2 - 64));
        if (r0 == i2) { dot0 = qn; q0 = qn; }
        if (r1 == i2) { dot1 = qn; q1 = qn; }

        // G updates: row i2 (contiguous b64), column i2
        *(float2*)&G[i2 * RSTR + r0] = make_float2(dot0, dot1);
        G[r0 * RSTR + i2] = dot0;
        G[r1 * RSTR + i2] = dot1;

        // cost values for row/col i2
        bool w0 = (s0 > 0.f) && r0 != i2 && r0 != j2;
        bool w1 = (s1 > 0.f) && r1 != i2 && r1 != j2;
        if (w0) {
            float d2 = q0 + qn - 2.0f * dot0;
            if (d2 < 0.f) d2 = 0.f;
            float w = (s0 * snew) / (s0 + snew + 1e-30f);
            float v0 = w * d2;
            cost[r0 * RSTR + i2] = v0;
            cost[i2 * RSTR + r0] = v0;
            if (!d0) {
                unsigned long long nk = mkkey(v0, r0, i2);
                if (nk < k0) k0 = nk;
            }
        }
        if (w1) {
            float d2 = q1 + qn - 2.0f * dot1;
            if (d2 < 0.f) d2 = 0.f;
            float w = (s1 * snew) / (s1 + snew + 1e-30f);
            float v1 = w * d2;
            cost[r1 * RSTR + i2] = v1;
            cost[i2 * RSTR + r1] = v1;
            if (!d1) {
                unsigned long long nk = mkkey(v1, r1, i2);
                if (nk < k1) k1 = nk;
            }
        }

        // rescans: row i2 (always) + dirty rows; 2 rows/round, b128 + alive-mask + u32 half-min
        bool pi = true;
        unsigned long long mm0 = m0, mm1 = m1;
        while (pi | (mm0 != 0ull) | (mm1 != 0ull)) {
            int rA, rB;
            bool hasB = false;
            if (pi) { rA = i2; pi = false; }
            else if (mm0) { int t = __ffsll(mm0) - 1; rA = 2 * t; mm0 &= mm0 - 1; }
            else { int t = __ffsll(mm1) - 1; rA = 2 * t + 1; mm1 &= mm1 - 1; }
            if (mm0) { int t = __ffsll(mm0) - 1; rB = 2 * t; mm0 &= mm0 - 1; hasB = true; }
            else if (mm1) { int t = __ffsll(mm1) - 1; rB = 2 * t + 1; mm1 &= mm1 - 1; hasB = true; }
            else rB = rA;

            int r = (lane < 32) ? rA : rB;
            float4 cv = *(const float4*)&cost[r * RSTR + 4 * hh];
            unsigned long long word = (hh < 16) ? alive0 : alive1;
            unsigned nib = (unsigned)(word >> ((4 * hh) & 63)) & 0xFu;
            unsigned e0 = (nib & 1u) ? __float_as_uint(cv.x) : 0xFFFFFFFFu;
            unsigned e1 = (nib & 2u) ? __float_as_uint(cv.y) : 0xFFFFFFFFu;
            unsigned e2 = (nib & 4u) ? __float_as_uint(cv.z) : 0xFFFFFFFFu;
            unsigned e3 = (nib & 8u) ? __float_as_uint(cv.w) : 0xFFFFFFFFu;
            unsigned m = e0; int c = 0;
            if (e1 < m) { m = e1; c = 1; }
            if (e2 < m) { m = e2; c = 2; }
            if (e3 < m) { m = e3; c = 3; }
            int lcol = 4 * hh + c;
            unsigned hm = half_umin(m);
            unsigned vA = (unsigned)__builtin_amdgcn_readlane((int)hm, 31);
            unsigned vB = (unsigned)__builtin_amdgcn_readlane((int)hm, 63);
            unsigned vref = (lane < 32) ? vA : vB;
            unsigned long long msk = __ballot(m == vref);
            int laneA = __ffsll(msk & 0xFFFFFFFFull) - 1;
            int laneB = 32 + __ffsll(msk >> 32) - 1;
            int colA = __builtin_amdgcn_readlane(lcol, laneA);
            int colB = __builtin_amdgcn_readlane(lcol, laneB);
            unsigned long long keyA = ((unsigned long long)vA << 32) | (unsigned)((rA << 7) | colA);
            unsigned long long keyB = ((unsigned long long)vB << 32) | (unsigned)((rB << 7) | colB);
            if (lane == (rA >> 1)) { if (rA & 1) k1 = keyA; else k0 = keyA; }
            if (hasB && lane == (rB >> 1)) { if (rB & 1) k1 = keyB; else k0 = keyB; }
        }
    }

    // final relabel
    szsE[r0] = s0;
    szsE[r1] = s1;
    __asm__ volatile("s_waitcnt lgkmcnt(0)" ::: "memory");
    if (lane == 0) {
        int c = 0;
        for (int i = 0; i < NPTS; ++i) rnk[i] = (szsE[i] > 0.f) ? c++ : -1;
    }
    __asm__ volatile("s_waitcnt lgkmcnt(0)" ::: "memory");
    out[b * NPTS + r0] = rnk[lab0];
    out[b * NPTS + r1] = rnk[lab1];
}

extern "C" void kernel_launch(void* const* d_in, const int* in_sizes, int n_in,
                              void* d_out, int out_size, void* d_ws, size_t ws_size,
                              hipStream_t stream) {
    const float* x  = (const float*)d_in[0];
    const float* W1 = (const float*)d_in[1];
    const float* b1 = (const float*)d_in[2];
    const float* W2 = (const float*)d_in[3];
    const float* b2 = (const float*)d_in[4];

    float* h = (float*)d_ws;                          // 16 MB
    float* feats = h + (size_t)MROWS * H1;            // 2 MB
    int* out = (int*)d_out;

    mlp1_kernel<<<dim3(MROWS / 64, H1 / 64), 256, 0, stream>>>(x, W1, b1, h);
    mlp2_kernel<<<MROWS / 16, 256, 0, stream>>>(h, W2, b2, feats);
    ward_kernel<<<BB, 256, 0, stream>>>(feats, out);
}

// Round 5
// 428.647 us; speedup vs baseline: 1.1717x; 1.0360x over previous
//
#include <hip/hip_runtime.h>
#include <math.h>

#define BB 128
#define NN 128
#define DIN 1024
#define H1 256
#define DOUT 32
#define KCL 8
#define NPTS 128
#define MROWS (BB*NN)   // 16384
#define CSTR 130        // centsT row stride (words, init staging only)
#define RSTR 132        // cost/G row stride (words, 16B aligned)
#define DEADKEY 0xFFFFFFFF00000000ull

__device__ __forceinline__ float gelu_exact(float v) {
    return 0.5f * v * (1.0f + erff(v * 0.70710678118654752f));
}

__device__ __forceinline__ unsigned long long mkkey(float v, int r, int j) {
    return ((unsigned long long)__float_as_uint(v) << 32) | (unsigned)((r << 7) | j);
}

__device__ __forceinline__ float readlanef(float v, int lane) {
    return __int_as_float(__builtin_amdgcn_readlane(__float_as_int(v), lane));
}

// u32 min via DPP (costs are >=0 floats: IEEE order == unsigned bit order)
template<int CTRL, int RMASK>
__device__ __forceinline__ unsigned dpp_umin_step(unsigned v) {
    unsigned t = (unsigned)__builtin_amdgcn_update_dpp((int)v, (int)v, CTRL, RMASK, 0xf, false);
    return t < v ? t : v;
}
__device__ __forceinline__ unsigned wave_umin_bcast(unsigned v) {
    v = dpp_umin_step<0x111, 0xf>(v);
    v = dpp_umin_step<0x112, 0xf>(v);
    v = dpp_umin_step<0x114, 0xf>(v);
    v = dpp_umin_step<0x118, 0xf>(v);
    v = dpp_umin_step<0x142, 0xa>(v);
    v = dpp_umin_step<0x143, 0xc>(v);
    return (unsigned)__builtin_amdgcn_readlane((int)v, 63);
}
// lane31 = min(lanes0..31), lane63 = min(lanes32..63)
__device__ __forceinline__ unsigned half_umin(unsigned v) {
    v = dpp_umin_step<0x111, 0xf>(v);
    v = dpp_umin_step<0x112, 0xf>(v);
    v = dpp_umin_step<0x114, 0xf>(v);
    v = dpp_umin_step<0x118, 0xf>(v);
    v = dpp_umin_step<0x142, 0xa>(v);
    return v;
}

// ---------------- gelu precompute: gx = gelu(x), memory-bound ----------------
__global__ __launch_bounds__(256) void gelu_kernel(const float* __restrict__ x,
                                                   float* __restrict__ gx, int n4) {
    int i = blockIdx.x * 256 + threadIdx.x;
    const int stride = gridDim.x * 256;
    for (; i < n4; i += stride) {
        float4 v = ((const float4*)x)[i];
        v.x = gelu_exact(v.x);
        v.y = gelu_exact(v.y);
        v.z = gelu_exact(v.z);
        v.w = gelu_exact(v.w);
        ((float4*)gx)[i] = v;
    }
}

// ---------------- GEMM1: h = A @ W1 + b1 ----------------
// 128x64 tile, 8x4 microtile, BK=32, R0 phase structure (load->sync->stage->sync->compute),
// grid (128,4)=512 blocks. LDS traffic: 3x ds_read_b128 per 32 FMA = 1.5 B/FMA
// (vs 2.0 for the 4x4 microtile) -- mlp1 is LDS-read-BW bound, so this is the lever.
// FUSE=true: A = gelu(x) at staging (fallback only). FUSE=false: A = gx (pre-gelu'd).
template<bool FUSE>
__global__ __launch_bounds__(256) void mlp1_kernel(const float* __restrict__ xin,
                                                   const float* __restrict__ W1,
                                                   const float* __restrict__ b1,
                                                   float* __restrict__ h) {
    __shared__ float As[32][132];  // [k][m] 16.9 KB
    __shared__ float Bs[32][68];   // [k][n]  8.7 KB
    const int bm = blockIdx.x;     // 128 row-tiles of 128
    const int bn = blockIdx.y;     // 4 col-tiles of 64
    const int tid = threadIdx.x;
    const int tx = tid & 15;       // col quad 0..15  (cols tx*4)
    const int ty = tid >> 4;       // row oct  0..15  (rows ty*8)

    float acc[8][4];
#pragma unroll
    for (int i = 0; i < 8; ++i)
#pragma unroll
        for (int j = 0; j < 4; ++j) acc[i][j] = 0.f;

    const int arow = tid >> 1;         // 0..127
    const int akb  = (tid & 1) * 16;   // k offset 0 or 16
    const int brow = tid >> 4;         // 0..15 (k)
    const int bcol4 = (tid & 15) * 4;  // 0..60

    const float* xrow = xin + (size_t)(bm * 128 + arow) * DIN;
    const float* wbase = W1 + bn * 64;

    for (int kt = 0; kt < DIN; kt += 32) {
        float4 a0 = *(const float4*)(xrow + kt + akb);
        float4 a1 = *(const float4*)(xrow + kt + akb + 4);
        float4 a2 = *(const float4*)(xrow + kt + akb + 8);
        float4 a3 = *(const float4*)(xrow + kt + akb + 12);
        float4 w0 = *(const float4*)(wbase + (size_t)(kt + brow) * H1 + bcol4);
        float4 w1 = *(const float4*)(wbase + (size_t)(kt + 16 + brow) * H1 + bcol4);
        __syncthreads();
        if (FUSE) {
            As[akb + 0][arow] = gelu_exact(a0.x);
            As[akb + 1][arow] = gelu_exact(a0.y);
            As[akb + 2][arow] = gelu_exact(a0.z);
            As[akb + 3][arow] = gelu_exact(a0.w);
            As[akb + 4][arow] = gelu_exact(a1.x);
            As[akb + 5][arow] = gelu_exact(a1.y);
            As[akb + 6][arow] = gelu_exact(a1.z);
            As[akb + 7][arow] = gelu_exact(a1.w);
            As[akb + 8][arow] = gelu_exact(a2.x);
            As[akb + 9][arow] = gelu_exact(a2.y);
            As[akb + 10][arow] = gelu_exact(a2.z);
            As[akb + 11][arow] = gelu_exact(a2.w);
            As[akb + 12][arow] = gelu_exact(a3.x);
            As[akb + 13][arow] = gelu_exact(a3.y);
            As[akb + 14][arow] = gelu_exact(a3.z);
            As[akb + 15][arow] = gelu_exact(a3.w);
        } else {
            As[akb + 0][arow] = a0.x;
            As[akb + 1][arow] = a0.y;
            As[akb + 2][arow] = a0.z;
            As[akb + 3][arow] = a0.w;
            As[akb + 4][arow] = a1.x;
            As[akb + 5][arow] = a1.y;
            As[akb + 6][arow] = a1.z;
            As[akb + 7][arow] = a1.w;
            As[akb + 8][arow] = a2.x;
            As[akb + 9][arow] = a2.y;
            As[akb + 10][arow] = a2.z;
            As[akb + 11][arow] = a2.w;
            As[akb + 12][arow] = a3.x;
            As[akb + 13][arow] = a3.y;
            As[akb + 14][arow] = a3.z;
            As[akb + 15][arow] = a3.w;
        }
        *(float4*)&Bs[brow][bcol4] = w0;
        *(float4*)&Bs[16 + brow][bcol4] = w1;
        __syncthreads();
#pragma unroll
        for (int kk = 0; kk < 32; ++kk) {
            float4 aL = *(const float4*)&As[kk][ty * 8];
            float4 aH = *(const float4*)&As[kk][ty * 8 + 4];
            float4 bv = *(const float4*)&Bs[kk][tx * 4];
            float ar[8] = {aL.x, aL.y, aL.z, aL.w, aH.x, aH.y, aH.z, aH.w};
            float br[4] = {bv.x, bv.y, bv.z, bv.w};
#pragma unroll
            for (int i = 0; i < 8; ++i)
#pragma unroll
                for (int j = 0; j < 4; ++j)
                    acc[i][j] = fmaf(ar[i], br[j], acc[i][j]);
        }
    }

    const int row0 = bm * 128 + ty * 8;
    const int col0 = bn * 64 + tx * 4;
    float4 bias = *(const float4*)(b1 + col0);
#pragma unroll
    for (int i = 0; i < 8; ++i) {
        float4 o;
        o.x = acc[i][0] + bias.x;
        o.y = acc[i][1] + bias.y;
        o.z = acc[i][2] + bias.z;
        o.w = acc[i][3] + bias.w;
        *(float4*)(h + (size_t)(row0 + i) * H1 + col0) = o;
    }
}

// ---------------- GEMM2: feats = gelu(h) @ W2 + b2 (best-measured R4 version) ----------------
__global__ __launch_bounds__(256) void mlp2_kernel(const float* __restrict__ h,
                                                   const float* __restrict__ W2,
                                                   const float* __restrict__ b2,
                                                   float* __restrict__ feats) {
    __shared__ float hs[16][257];
    __shared__ float w2s[H1 * DOUT];
    const int blk = blockIdx.x;
    const int tid = threadIdx.x;

    for (int i = tid; i < (H1 * DOUT) / 4; i += 256) {
        ((float4*)w2s)[i] = ((const float4*)W2)[i];
    }
    const float* hb = h + (size_t)blk * 16 * H1;
    for (int i = tid; i < (16 * H1) / 4; i += 256) {
        float4 v = ((const float4*)hb)[i];
        int r = i >> 6;
        int c = (i & 63) * 4;
        hs[r][c + 0] = gelu_exact(v.x);
        hs[r][c + 1] = gelu_exact(v.y);
        hs[r][c + 2] = gelu_exact(v.z);
        hs[r][c + 3] = gelu_exact(v.w);
    }
    __syncthreads();

    const int col = tid & 31;
    const int r0 = (tid >> 5) * 2;
    float acc0 = 0.f, acc1 = 0.f;
    for (int k = 0; k < H1; ++k) {
        float w = w2s[k * DOUT + col];
        acc0 = fmaf(hs[r0 + 0][k], w, acc0);
        acc1 = fmaf(hs[r0 + 1][k], w, acc1);
    }
    float bias = b2[col];
    const int rowg = blk * 16 + r0;
    feats[(size_t)(rowg + 0) * DOUT + col] = acc0 + bias;
    feats[(size_t)(rowg + 1) * DOUT + col] = acc1 + bias;
}

// ---------------- Ward clustering: incremental Gram, i2 folded into rescan loop ----------------
__global__ __launch_bounds__(256) void ward_kernel(const float* __restrict__ feats,
                                                   int* __restrict__ out) {
    __shared__ __align__(16) float cost[NPTS * RSTR];  // 67.6 KB
    __shared__ __align__(16) float G[NPTS * RSTR];     // 67.6 KB Gram matrix
    __shared__ float centsT[32 * CSTR];                // init staging only
    __shared__ unsigned long long rowkey[NPTS];
    __shared__ float sqArr[NPTS];
    __shared__ float szsE[NPTS];
    __shared__ int rnk[NPTS];

    const int b = blockIdx.x;
    const int tid = threadIdx.x;
    const float* f = feats + (size_t)b * NPTS * DOUT;
    const float INF = __builtin_inff();

    // ---- init (all 4 waves) ----
    for (int i = tid; i < NPTS * DOUT; i += 256) {
        int r = i >> 5, d = i & 31;
        centsT[d * CSTR + r] = f[i];
    }
    __syncthreads();
    if (tid < NPTS) {
        float s = 0.f;
#pragma unroll
        for (int d = 0; d < 32; ++d) {
            float v = centsT[d * CSTR + tid];
            s = fmaf(v, v, s);
        }
        sqArr[tid] = s;
    }
    __syncthreads();
    {
        int ti = tid >> 4, tj = tid & 15;
        int I0 = ti * 8, J0 = tj * 8;
        float acc[8][8];
#pragma unroll
        for (int u = 0; u < 8; ++u)
#pragma unroll
            for (int v = 0; v < 8; ++v) acc[u][v] = 0.f;
        for (int d = 0; d < 32; ++d) {
            float a[8], bb[8];
#pragma unroll
            for (int u = 0; u < 8; ++u) a[u] = centsT[d * CSTR + I0 + u];
#pragma unroll
            for (int v = 0; v < 8; ++v) bb[v] = centsT[d * CSTR + J0 + v];
#pragma unroll
            for (int u = 0; u < 8; ++u)
#pragma unroll
                for (int v = 0; v < 8; ++v)
                    acc[u][v] = fmaf(a[u], bb[v], acc[u][v]);
        }
#pragma unroll
        for (int u = 0; u < 8; ++u) {
#pragma unroll
            for (int v = 0; v < 8; ++v) {
                int i = I0 + u, j = J0 + v;
                G[i * RSTR + j] = acc[u][v];
                float d2 = sqArr[i] + sqArr[j] - 2.0f * acc[u][v];
                if (d2 < 0.f) d2 = 0.f;
                float w = (1.0f * 1.0f) / (1.0f + 1.0f + 1e-30f);
                cost[i * RSTR + j] = (i == j) ? INF : w * d2;
            }
        }
    }
    __syncthreads();
    if (tid < NPTS) {
        unsigned long long best = DEADKEY;
        for (int j = 0; j < NPTS; ++j) {
            float v = cost[tid * RSTR + j];
            unsigned long long k = mkkey(v, tid, j);
            if (k < best) best = k;
        }
        rowkey[tid] = best;
    }
    __syncthreads();

    if (tid >= 64) return;  // wave 0 only
    const int lane = tid;
    const int hh = lane & 31;
    const int r0 = lane * 2, r1 = lane * 2 + 1;

    unsigned long long k0 = rowkey[r0], k1 = rowkey[r1];
    float q0 = sqArr[r0], q1 = sqArr[r1];
    float s0 = 1.0f, s1 = 1.0f;
    int lab0 = r0, lab1 = r1;
    unsigned long long alive0 = ~0ull, alive1 = ~0ull;

    for (int it = 0; it < NPTS - KCL; ++it) {
        // P1: global argmin via u32-bits DPP min + ballot (exact flat-index tie-break)
        unsigned bv0 = (unsigned)(k0 >> 32), bv1 = (unsigned)(k1 >> 32);
        unsigned lmin = bv0 < bv1 ? bv0 : bv1;
        unsigned lflat = (bv0 <= bv1) ? (unsigned)(k0 & 0x3FFFu) : (unsigned)(k1 & 0x3FFFu);
        unsigned gmin = wave_umin_bcast(lmin);
        unsigned long long bmask = __ballot(lmin == gmin);
        int lsel = __ffsll(bmask) - 1;
        unsigned flat = (unsigned)__builtin_amdgcn_readlane((int)lflat, lsel);
        int ra = (int)(flat >> 7), ca = (int)(flat & 127u);
        const int i2 = ra < ca ? ra : ca;
        const int j2 = ra < ca ? ca : ra;

        // Gram rows i2, j2 (issued early; only depend on i2/j2)
        float2 gi = *(const float2*)&G[i2 * RSTR + r0];
        float2 gj = *(const float2*)&G[j2 * RSTR + r0];

        float si = readlanef((i2 & 1) ? s1 : s0, i2 >> 1);
        float sj = readlanef((j2 & 1) ? s1 : s0, j2 >> 1);
        const float snew = si + sj;
        const float invs = 1.0f / snew;
        const float wa = si * invs, wb = sj * invs;

        int arg0 = (int)(k0 & 127u), arg1 = (int)(k1 & 127u);
        bool d0 = (s0 > 0.f) && r0 != i2 && r0 != j2 && (arg0 == i2 || arg0 == j2);
        bool d1 = (s1 > 0.f) && r1 != i2 && r1 != j2 && (arg1 == i2 || arg1 == j2);
        unsigned long long m0 = __ballot(d0), m1 = __ballot(d1);

        // scalar Gram entries for qn
        float Gii = readlanef((i2 & 1) ? gi.y : gi.x, i2 >> 1);
        float Gij = readlanef((i2 & 1) ? gj.y : gj.x, i2 >> 1);
        float Gjj = readlanef((j2 & 1) ? gj.y : gj.x, j2 >> 1);
        float dotA = wa * Gii + wb * Gij;
        float dotB = wa * Gij + wb * Gjj;
        float qn = wa * dotA + wb * dotB;

        // per-lane dots with merged cluster (linear Gram update)
        float dot0 = wa * gi.x + wb * gj.x;
        float dot1 = wa * gi.y + wb * gj.y;

        // state updates
        if (lab0 == j2) lab0 = i2;
        if (lab1 == j2) lab1 = i2;
        if (r0 == i2) s0 = snew; else if (r0 == j2) { s0 = 0.f; k0 = DEADKEY; }
        if (r1 == i2) s1 = snew; else if (r1 == j2) { s1 = 0.f; k1 = DEADKEY; }
        if (j2 < 64) alive0 &= ~(1ull << j2); else alive1 &= ~(1ull << (j2 - 64));
        if (r0 == i2) { dot0 = qn; q0 = qn; }
        if (r1 == i2) { dot1 = qn; q1 = qn; }

        // G updates: row i2 (contiguous b64), column i2
        *(float2*)&G[i2 * RSTR + r0] = make_float2(dot0, dot1);
        G[r0 * RSTR + i2] = dot0;
        G[r1 * RSTR + i2] = dot1;

        // cost values for row/col i2
        bool w0 = (s0 > 0.f) && r0 != i2 && r0 != j2;
        bool w1 = (s1 > 0.f) && r1 != i2 && r1 != j2;
        if (w0) {
            float d2 = q0 + qn - 2.0f * dot0;
            if (d2 < 0.f) d2 = 0.f;
            float w = (s0 * snew) / (s0 + snew + 1e-30f);
            float v0 = w * d2;
            cost[r0 * RSTR + i2] = v0;
            cost[i2 * RSTR + r0] = v0;
            if (!d0) {
                unsigned long long nk = mkkey(v0, r0, i2);
                if (nk < k0) k0 = nk;
            }
        }
        if (w1) {
            float d2 = q1 + qn - 2.0f * dot1;
            if (d2 < 0.f) d2 = 0.f;
            float w = (s1 * snew) / (s1 + snew + 1e-30f);
            float v1 = w * d2;
            cost[r1 * RSTR + i2] = v1;
            cost[i2 * RSTR + r1] = v1;
            if (!d1) {
                unsigned long long nk = mkkey(v1, r1, i2);
                if (nk < k1) k1 = nk;
            }
        }

        // rescans: row i2 (always) + dirty rows; 2 rows/round, b128 + alive-mask + u32 half-min
        bool pi = true;
        unsigned long long mm0 = m0, mm1 = m1;
        while (pi | (mm0 != 0ull) | (mm1 != 0ull)) {
            int rA, rB;
            bool hasB = false;
            if (pi) { rA = i2; pi = false; }
            else if (mm0) { int t = __ffsll(mm0) - 1; rA = 2 * t; mm0 &= mm0 - 1; }
            else { int t = __ffsll(mm1) - 1; rA = 2 * t + 1; mm1 &= mm1 - 1; }
            if (mm0) { int t = __ffsll(mm0) - 1; rB = 2 * t; mm0 &= mm0 - 1; hasB = true; }
            else if (mm1) { int t = __ffsll(mm1) - 1; rB = 2 * t + 1; mm1 &= mm1 - 1; hasB = true; }
            else rB = rA;

            int r = (lane < 32) ? rA : rB;
            float4 cv = *(const float4*)&cost[r * RSTR + 4 * hh];
            unsigned long long word = (hh < 16) ? alive0 : alive1;
            unsigned nib = (unsigned)(word >> ((4 * hh) & 63)) & 0xFu;
            unsigned e0 = (nib & 1u) ? __float_as_uint(cv.x) : 0xFFFFFFFFu;
            unsigned e1 = (nib & 2u) ? __float_as_uint(cv.y) : 0xFFFFFFFFu;
            unsigned e2 = (nib & 4u) ? __float_as_uint(cv.z) : 0xFFFFFFFFu;
            unsigned e3 = (nib & 8u) ? __float_as_uint(cv.w) : 0xFFFFFFFFu;
            unsigned m = e0; int c = 0;
            if (e1 < m) { m = e1; c = 1; }
            if (e2 < m) { m = e2; c = 2; }
            if (e3 < m) { m = e3; c = 3; }
            int lcol = 4 * hh + c;
            unsigned hm = half_umin(m);
            unsigned vA = (unsigned)__builtin_amdgcn_readlane((int)hm, 31);
            unsigned vB = (unsigned)__builtin_amdgcn_readlane((int)hm, 63);
            unsigned vref = (lane < 32) ? vA : vB;
            unsigned long long msk = __ballot(m == vref);
            int laneA = __ffsll(msk & 0xFFFFFFFFull) - 1;
            int laneB = 32 + __ffsll(msk >> 32) - 1;
            int colA = __builtin_amdgcn_readlane(lcol, laneA);
            int colB = __builtin_amdgcn_readlane(lcol, laneB);
            unsigned long long keyA = ((unsigned long long)vA << 32) | (unsigned)((rA << 7) | colA);
            unsigned long long keyB = ((unsigned long long)vB << 32) | (unsigned)((rB << 7) | colB);
            if (lane == (rA >> 1)) { if (rA & 1) k1 = keyA; else k0 = keyA; }
            if (hasB && lane == (rB >> 1)) { if (rB & 1) k1 = keyB; else k0 = keyB; }
        }
    }

    // final relabel
    szsE[r0] = s0;
    szsE[r1] = s1;
    __asm__ volatile("s_waitcnt lgkmcnt(0)" ::: "memory");
    if (lane == 0) {
        int c = 0;
        for (int i = 0; i < NPTS; ++i) rnk[i] = (szsE[i] > 0.f) ? c++ : -1;
    }
    __asm__ volatile("s_waitcnt lgkmcnt(0)" ::: "memory");
    out[b * NPTS + r0] = rnk[lab0];
    out[b * NPTS + r1] = rnk[lab1];
}

extern "C" void kernel_launch(void* const* d_in, const int* in_sizes, int n_in,
                              void* d_out, int out_size, void* d_ws, size_t ws_size,
                              hipStream_t stream) {
    const float* x  = (const float*)d_in[0];
    const float* W1 = (const float*)d_in[1];
    const float* b1 = (const float*)d_in[2];
    const float* W2 = (const float*)d_in[3];
    const float* b2 = (const float*)d_in[4];

    float* h = (float*)d_ws;                          // 16 MB
    float* feats = h + (size_t)MROWS * H1;            // 2 MB
    float* gx = feats + (size_t)MROWS * DOUT;         // 64 MB (if it fits)
    int* out = (int*)d_out;

    const size_t need = ((size_t)MROWS * H1 + (size_t)MROWS * DOUT + (size_t)MROWS * DIN) * 4;
    const bool use_gx = ws_size >= need;

    if (use_gx) {
        gelu_kernel<<<2048, 256, 0, stream>>>(x, gx, MROWS * DIN / 4);
        mlp1_kernel<false><<<dim3(MROWS / 128, H1 / 64), 256, 0, stream>>>(gx, W1, b1, h);
    } else {
        mlp1_kernel<true><<<dim3(MROWS / 128, H1 / 64), 256, 0, stream>>>(x, W1, b1, h);
    }
    mlp2_kernel<<<MROWS / 16, 256, 0, stream>>>(h, W2, b2, feats);
    ward_kernel<<<BB, 256, 0, stream>>>(feats, out);
}